// Round 1
// baseline (368.518 us; speedup 1.0000x reference)
//
#include <hip/hip_runtime.h>
#include <cstdint>

#define NTOT 73728      // B*H*W = 32*48*48
#define CTOT 512
#define MGRP 128        // members per group
#define EPSV 1e-7f

typedef float4 f4;
__device__ __forceinline__ f4 ld4(const float* p){ return *(const f4*)p; }
__device__ __forceinline__ void st4(float* p, f4 v){ *(f4*)p = v; }

// ---------------- K1: per-chunk Sxx partials + Sx partials ----------------
// grid (nchunk, 4), block 512. Each block: rowsPer rows of one group's 128 cols.
// Thread tile: 8 rows(i) x 4 cols(j) of the 128x128 outer-product accumulator.
__global__ __launch_bounds__(512) void k_cov_partial(
    const float* __restrict__ x, float* __restrict__ sxxPart,
    float* __restrict__ sxPart, int nchunk, int rowsPer)
{
    const int chunk = blockIdx.x, g = blockIdx.y;
    const int t  = threadIdx.x;
    const int ty = t >> 5;          // 0..15 -> i-range ty*8..+7
    const int tx = t & 31;          // 0..31 -> j-range tx*4..+3
    const int lr = t >> 5;          // loader row 0..15
    const int cq = t & 31;          // loader col-quad

    __shared__ float rows[16][128];
    __shared__ f4 sxbuf[512];

    const float* xg = x + (size_t)chunk * rowsPer * CTOT + (size_t)g * MGRP;
    const float* lp = xg + (size_t)lr * CTOT + cq * 4;

    float acc[8][4];
#pragma unroll
    for (int i = 0; i < 8; ++i)
#pragma unroll
        for (int j = 0; j < 4; ++j) acc[i][j] = 0.f;
    f4 sx = {0.f, 0.f, 0.f, 0.f};

    f4 v = ld4(lp);                       // software-pipelined prefetch
    for (int r0 = 0; r0 < rowsPer; r0 += 16) {
        sx.x += v.x; sx.y += v.y; sx.z += v.z; sx.w += v.w;
        st4(&rows[lr][cq * 4], v);
        __syncthreads();
        if (r0 + 16 < rowsPer) v = ld4(lp + (size_t)(r0 + 16) * CTOT);
#pragma unroll
        for (int r = 0; r < 16; ++r) {
            f4 a0 = ld4(&rows[r][ty * 8]);
            f4 a1 = ld4(&rows[r][ty * 8 + 4]);
            f4 b0 = ld4(&rows[r][tx * 4]);
            float av[8] = {a0.x, a0.y, a0.z, a0.w, a1.x, a1.y, a1.z, a1.w};
            float bv[4] = {b0.x, b0.y, b0.z, b0.w};
#pragma unroll
            for (int i = 0; i < 8; ++i)
#pragma unroll
                for (int j = 0; j < 4; ++j) acc[i][j] += av[i] * bv[j];
        }
        __syncthreads();
    }

    float* op = sxxPart + ((size_t)g * nchunk + chunk) * 16384;
#pragma unroll
    for (int i = 0; i < 8; ++i) {
        int rowi = ty * 8 + i;
        f4 c0 = {acc[i][0], acc[i][1], acc[i][2], acc[i][3]};
        st4(&op[rowi * 128 + tx * 4], c0);
    }

    sxbuf[t] = sx;
    __syncthreads();
    if (t < 32) {
        f4 s = sxbuf[t];
#pragma unroll
        for (int r = 1; r < 16; ++r) {
            f4 u = sxbuf[t + 32 * r];
            s.x += u.x; s.y += u.y; s.z += u.z; s.w += u.w;
        }
        st4(&sxPart[((size_t)g * nchunk + chunk) * 128 + t * 4], s);
    }
}

// ---------------- K2: reduce Sxx partials over chunks ----------------
// grid (64, 4), block 256 -> each thread one of 16384 elements.
__global__ __launch_bounds__(256) void k_reduce(
    const float* __restrict__ sxxPart, float* __restrict__ gSxx, int nchunk)
{
    int g = blockIdx.y;
    int idx = blockIdx.x * 256 + threadIdx.x;
    float s = 0.f;
    for (int c = 0; c < nchunk; ++c)
        s += sxxPart[((size_t)g * nchunk + c) * 16384 + idx];
    gSxx[g * 16384 + idx] = s;
}

// ---------------- K3: finalize -> mean, trace, sigma, P1 ----------------
__global__ __launch_bounds__(256) void k_finalize(
    const float* __restrict__ gSxx, const float* __restrict__ sxPart,
    float* __restrict__ gSigma, float* __restrict__ gP,
    float* __restrict__ gMean, float* __restrict__ gScale, int nchunk)
{
    int g = blockIdx.x, t = threadIdx.x;
    __shared__ float mu[128];
    __shared__ float red[256];

    if (t < 128) {
        float s = 0.f;
        for (int c = 0; c < nchunk; ++c)
            s += sxPart[((size_t)g * nchunk + c) * 128 + t];
        float m = s / (float)NTOT;
        mu[t] = m;
        gMean[g * 128 + t] = m;
    }
    __syncthreads();

    float d = 0.f;
    if (t < 128) {
        float vdiag = gSxx[g * 16384 + t * 128 + t];
        float cv = (vdiag - (float)NTOT * mu[t] * mu[t]) / ((float)NTOT - 1.f);
        d = (1.f - EPSV) * cv + EPSV;   // blended diagonal
    }
    red[t] = d;
    __syncthreads();
    for (int s = 128; s > 0; s >>= 1) {
        if (t < s) red[t] += red[t + s];
        __syncthreads();
    }
    float tr = red[0];
    float invTr = 1.f / tr;
    if (t == 0) gScale[g] = rsqrtf(tr);

    for (int e = t; e < 16384; e += 256) {
        int i = e >> 7, j = e & 127;
        float cv = (gSxx[g * 16384 + e] - (float)NTOT * mu[i] * mu[j]) / ((float)NTOT - 1.f);
        float ce = (1.f - EPSV) * cv + ((i == j) ? EPSV : 0.f);
        float sg = ce * invTr;
        gSigma[g * 16384 + e] = sg;
        gP[g * 16384 + e] = ((i == j) ? 1.5f : 0.f) - 0.5f * sg;  // first NS iterate
    }
}

// ---------------- K4: P2 = P@P, PS = P@Sigma ----------------
// grid (16, 4), block 256: 8 output rows per block, 4 cols per thread, both mats.
__global__ __launch_bounds__(256) void k_ns1(
    const float* __restrict__ gP, const float* __restrict__ gS,
    float* __restrict__ gP2, float* __restrict__ gPS)
{
    int g = blockIdx.y;
    int row = blockIdx.x * 8 + (threadIdx.x >> 5);
    int cq = (threadIdx.x & 31) * 4;
    const float* P = gP + g * 16384;
    const float* S = gS + g * 16384;
    f4 a1 = {0.f,0.f,0.f,0.f}, a2 = {0.f,0.f,0.f,0.f};
    for (int k = 0; k < 128; k += 4) {
        f4 a = ld4(&P[row * 128 + k]);
        float av[4] = {a.x, a.y, a.z, a.w};
#pragma unroll
        for (int kk = 0; kk < 4; ++kk) {
            f4 b1 = ld4(&P[(k + kk) * 128 + cq]);
            f4 b2 = ld4(&S[(k + kk) * 128 + cq]);
            float aa = av[kk];
            a1.x += aa * b1.x; a1.y += aa * b1.y; a1.z += aa * b1.z; a1.w += aa * b1.w;
            a2.x += aa * b2.x; a2.y += aa * b2.y; a2.z += aa * b2.z; a2.w += aa * b2.w;
        }
    }
    st4(&gP2[g * 16384 + row * 128 + cq], a1);
    st4(&gPS[g * 16384 + row * 128 + cq], a2);
}

// ---------------- K5: P = 1.5P - 0.5 * (P2 @ PS) ----------------
__global__ __launch_bounds__(256) void k_ns2(
    float* __restrict__ gP, const float* __restrict__ gP2, const float* __restrict__ gPS)
{
    int g = blockIdx.y;
    int row = blockIdx.x * 8 + (threadIdx.x >> 5);
    int cq = (threadIdx.x & 31) * 4;
    const float* A = gP2 + g * 16384;
    const float* B = gPS + g * 16384;
    f4 acc = {0.f,0.f,0.f,0.f};
    for (int k = 0; k < 128; k += 4) {
        f4 a = ld4(&A[row * 128 + k]);
        float av[4] = {a.x, a.y, a.z, a.w};
#pragma unroll
        for (int kk = 0; kk < 4; ++kk) {
            f4 b = ld4(&B[(k + kk) * 128 + cq]);
            float aa = av[kk];
            acc.x += aa * b.x; acc.y += aa * b.y; acc.z += aa * b.z; acc.w += aa * b.w;
        }
    }
    size_t off = (size_t)g * 16384 + row * 128 + cq;
    f4 p = ld4(&gP[off]);
    f4 r;
    r.x = 1.5f * p.x - 0.5f * acc.x;
    r.y = 1.5f * p.y - 0.5f * acc.y;
    r.z = 1.5f * p.z - 0.5f * acc.z;
    r.w = 1.5f * p.w - 0.5f * acc.w;
    st4(&gP[off], r);
}

// ---------------- K6: beta' = beta - gamma * (W @ mu),  W = P*scale ----------------
__global__ __launch_bounds__(128) void k_bprime(
    const float* __restrict__ gP, const float* __restrict__ gMean,
    const float* __restrict__ gScale, const float* __restrict__ gamma,
    const float* __restrict__ beta, float* __restrict__ gBp)
{
    int g = blockIdx.x, j = threadIdx.x;
    float s = 0.f;
    for (int k = 0; k < 128; ++k)
        s += gMean[g * 128 + k] * gP[g * 16384 + k * 128 + j];
    s *= gScale[g];
    int c = g * 128 + j;
    gBp[c] = beta[c] - gamma[c] * s;
}

// ---------------- K7: out = gamma * (X @ W) + beta' ----------------
// grid (NTOT/64, 4), block 512. W staged in LDS (64KB). Thread tile 4 rows x 4 cols.
__global__ __launch_bounds__(512) void k_apply(
    const float* __restrict__ x, const float* __restrict__ gP,
    const float* __restrict__ gScale, const float* __restrict__ gamma,
    const float* __restrict__ gBp, float* __restrict__ out)
{
    int g = blockIdx.y;
    int n0 = blockIdx.x * 64;
    int t = threadIdx.x;
    __shared__ float W[16384];

    float sc = gScale[g];
    const f4* P4 = (const f4*)(gP + g * 16384);
    f4* W4 = (f4*)W;
#pragma unroll
    for (int i = 0; i < 8; ++i) {
        int q = t + 512 * i;
        f4 v = P4[q];
        v.x *= sc; v.y *= sc; v.z *= sc; v.w *= sc;
        W4[q] = v;
    }
    __syncthreads();

    int ty = t >> 5;   // 0..15 -> rows 4*ty..+3
    int tx = t & 31;   // 0..31 -> cols 4*tx..+3
    const float* xg = x + (size_t)n0 * CTOT + g * MGRP;

    f4 acc[4];
#pragma unroll
    for (int i = 0; i < 4; ++i) acc[i] = {0.f, 0.f, 0.f, 0.f};

    for (int k = 0; k < 128; k += 4) {
        f4 a[4];
#pragma unroll
        for (int i = 0; i < 4; ++i)
            a[i] = ld4(&xg[(size_t)(4 * ty + i) * CTOT + k]);
#pragma unroll
        for (int kk = 0; kk < 4; ++kk) {
            f4 w = ld4(&W[(k + kk) * 128 + tx * 4]);
#pragma unroll
            for (int i = 0; i < 4; ++i) {
                float aa = (kk == 0) ? a[i].x : (kk == 1) ? a[i].y : (kk == 2) ? a[i].z : a[i].w;
                acc[i].x += aa * w.x; acc[i].y += aa * w.y;
                acc[i].z += aa * w.z; acc[i].w += aa * w.w;
            }
        }
    }

    int c0 = g * MGRP + tx * 4;
    f4 gm = ld4(&gamma[c0]);
    f4 bp = ld4(&gBp[c0]);
#pragma unroll
    for (int i = 0; i < 4; ++i) {
        f4 r;
        r.x = gm.x * acc[i].x + bp.x;
        r.y = gm.y * acc[i].y + bp.y;
        r.z = gm.z * acc[i].z + bp.z;
        r.w = gm.w * acc[i].w + bp.w;
        st4(&out[(size_t)(n0 + 4 * ty + i) * CTOT + c0], r);
    }
}

// ---------------- launch ----------------
extern "C" void kernel_launch(void* const* d_in, const int* in_sizes, int n_in,
                              void* d_out, int out_size, void* d_ws, size_t ws_size,
                              hipStream_t stream)
{
    const float* x     = (const float*)d_in[0];
    const float* gamma = (const float*)d_in[1];
    const float* beta  = (const float*)d_in[2];
    float* out = (float*)d_out;
    float* ws  = (float*)d_ws;

    // pick chunk count that fits workspace (partials dominate)
    int nchunk = 64;
    auto need = [](int nc) -> size_t {
        return ((size_t)nc * 4 * 16384 + (size_t)nc * 4 * 128 +
                5ull * 4 * 16384 + 512 + 16 + 512) * 4;
    };
    while (nchunk > 8 && need(nchunk) > ws_size) nchunk >>= 1;
    int rowsPer = NTOT / nchunk;

    size_t off = 0;
    float* sxxPart = ws + off; off += (size_t)nchunk * 4 * 16384;
    float* sxPart  = ws + off; off += (size_t)nchunk * 4 * 128;
    float* gSxx    = ws + off; off += 4 * 16384;
    float* gSigma  = ws + off; off += 4 * 16384;
    float* gP      = ws + off; off += 4 * 16384;
    float* gP2     = ws + off; off += 4 * 16384;
    float* gPS     = ws + off; off += 4 * 16384;
    float* gMean   = ws + off; off += 512;
    float* gScale  = ws + off; off += 16;
    float* gBp     = ws + off; off += 512;

    k_cov_partial<<<dim3(nchunk, 4), 512, 0, stream>>>(x, sxxPart, sxPart, nchunk, rowsPer);
    k_reduce<<<dim3(64, 4), 256, 0, stream>>>(sxxPart, gSxx, nchunk);
    k_finalize<<<4, 256, 0, stream>>>(gSxx, sxPart, gSigma, gP, gMean, gScale, nchunk);
    for (int it = 0; it < 2; ++it) {
        k_ns1<<<dim3(16, 4), 256, 0, stream>>>(gP, gSigma, gP2, gPS);
        k_ns2<<<dim3(16, 4), 256, 0, stream>>>(gP, gP2, gPS);
    }
    k_bprime<<<4, 128, 0, stream>>>(gP, gMean, gScale, gamma, beta, gBp);
    k_apply<<<dim3(NTOT / 64, 4), 512, 0, stream>>>(x, gP, gScale, gamma, gBp, out);
}

// Round 2
// 204.653 us; speedup vs baseline: 1.8007x; 1.8007x over previous
//
#include <hip/hip_runtime.h>
#include <cstdint>

#define NTOT 73728      // B*H*W = 32*48*48
#define CTOT 512
#define MGRP 128        // members per group
#define EPSV 1e-7f
#define LDP  40         // padded LDS row stride in bf16 (80 bytes: 2-way banks, 16B-aligned)

typedef float4 f4;
typedef __attribute__((ext_vector_type(8))) short bf16x8;  // 8 bf16 (4 VGPRs)
typedef __attribute__((ext_vector_type(4))) float f32x4;   // MFMA accumulator

__device__ __forceinline__ f4 ld4(const float* p){ return *(const f4*)p; }

__device__ __forceinline__ ushort f2bf(float f){  // RNE fp32 -> bf16
    uint32_t u = __builtin_bit_cast(uint32_t, f);
    uint32_t r = (u + 0x7FFFu + ((u >> 16) & 1u)) >> 16;
    return (ushort)r;
}

// ---------------- K1: per-chunk Sxx partials (MFMA) + Sx partials ----------------
// grid (nchunk, 4), block 512 (8 waves, 2x4 wave grid; each wave 64x32 of the 128x128 output).
// LDS tile: 32 samples x 128 channels bf16, stored [channel][sample], stride LDP=40.
__global__ __launch_bounds__(512) void k_cov(
    const float* __restrict__ x, float* __restrict__ sxxPart,
    float* __restrict__ sxPart, int nchunk, int rowsPer)
{
    const int chunk = blockIdx.x, g = blockIdx.y;
    const int t = threadIdx.x;
    const int lane = t & 63, wid = t >> 6;
    const int wm = wid >> 2, wn = wid & 3;       // wave grid 2 (rows) x 4 (cols)
    const int l15 = lane & 15, l4 = lane >> 4;   // frag row/col, k-quad

    __shared__ ushort xs[128 * LDP];             // 10,240 B
    __shared__ float sxbuf[512];

    const int c  = t & 127;                      // staging: channel
    const int nq = t >> 7;                       // staging: sample-octet 0..3
    const float* xp = x + ((size_t)chunk * rowsPer + nq * 8) * CTOT + (size_t)g * MGRP + c;

    f32x4 acc[4][2];
#pragma unroll
    for (int i = 0; i < 4; ++i)
#pragma unroll
        for (int j = 0; j < 2; ++j) acc[i][j] = (f32x4){0.f, 0.f, 0.f, 0.f};
    float sx = 0.f;

    float v[8];
#pragma unroll
    for (int e = 0; e < 8; ++e) v[e] = xp[(size_t)e * CTOT];

    const int niter = rowsPer / 32;
    for (int it = 0; it < niter; ++it) {
        uint32_t pk[4];
#pragma unroll
        for (int e = 0; e < 4; ++e) {
            sx += v[2*e] + v[2*e+1];
            pk[e] = (uint32_t)f2bf(v[2*e]) | ((uint32_t)f2bf(v[2*e+1]) << 16);
        }
        if (it) __syncthreads();                 // previous tile's reads done
        *(uint4*)&xs[c * LDP + nq * 8] = make_uint4(pk[0], pk[1], pk[2], pk[3]);
        __syncthreads();
        if (it + 1 < niter) {
            const float* np = xp + (size_t)(it + 1) * 32 * CTOT;
#pragma unroll
            for (int e = 0; e < 8; ++e) v[e] = np[(size_t)e * CTOT];
        }
        bf16x8 af[4], bfr[2];
#pragma unroll
        for (int tm = 0; tm < 4; ++tm)
            af[tm] = *(const bf16x8*)&xs[(wm*64 + tm*16 + l15) * LDP + l4*8];
#pragma unroll
        for (int tn = 0; tn < 2; ++tn)
            bfr[tn] = *(const bf16x8*)&xs[(wn*32 + tn*16 + l15) * LDP + l4*8];
#pragma unroll
        for (int tm = 0; tm < 4; ++tm)
#pragma unroll
            for (int tn = 0; tn < 2; ++tn)
                acc[tm][tn] = __builtin_amdgcn_mfma_f32_16x16x32_bf16(
                    af[tm], bfr[tn], acc[tm][tn], 0, 0, 0);
    }

    float* op = sxxPart + ((size_t)g * nchunk + chunk) * 16384;
#pragma unroll
    for (int tm = 0; tm < 4; ++tm)
#pragma unroll
        for (int tn = 0; tn < 2; ++tn)
#pragma unroll
            for (int r = 0; r < 4; ++r) {
                int i = wm*64 + tm*16 + l4*4 + r;   // D row = (lane>>4)*4 + reg
                int j = wn*32 + tn*16 + l15;        // D col = lane&15
                op[i * 128 + j] = acc[tm][tn][r];
            }

    sxbuf[t] = sx;
    __syncthreads();
    if (t < 128) {
        float s = sxbuf[t] + sxbuf[t + 128] + sxbuf[t + 256] + sxbuf[t + 384];
        sxPart[((size_t)g * nchunk + chunk) * 128 + t] = s;
    }
}

// ---------------- K2: reduce Sxx partials over chunks ----------------
__global__ __launch_bounds__(256) void k_reduce(
    const float* __restrict__ sxxPart, float* __restrict__ gSxx, int nchunk)
{
    int g = blockIdx.y;
    int idx = blockIdx.x * 256 + threadIdx.x;
    float s = 0.f;
    for (int c = 0; c < nchunk; ++c)
        s += sxxPart[((size_t)g * nchunk + c) * 16384 + idx];
    gSxx[g * 16384 + idx] = s;
}

// ---------------- K3: finalize -> mean, trace, sigma, P1 ----------------
__global__ __launch_bounds__(256) void k_finalize(
    const float* __restrict__ gSxx, const float* __restrict__ sxPart,
    float* __restrict__ gSigma, float* __restrict__ gP,
    float* __restrict__ gMean, float* __restrict__ gScale, int nchunk)
{
    int g = blockIdx.x, t = threadIdx.x;
    __shared__ float mu[128];
    __shared__ float red[256];

    if (t < 128) {
        float s = 0.f;
        for (int c = 0; c < nchunk; ++c)
            s += sxPart[((size_t)g * nchunk + c) * 128 + t];
        float m = s / (float)NTOT;
        mu[t] = m;
        gMean[g * 128 + t] = m;
    }
    __syncthreads();

    float d = 0.f;
    if (t < 128) {
        float vdiag = gSxx[g * 16384 + t * 128 + t];
        float cv = (vdiag - (float)NTOT * mu[t] * mu[t]) / ((float)NTOT - 1.f);
        d = (1.f - EPSV) * cv + EPSV;
    }
    red[t] = d;
    __syncthreads();
    for (int s = 128; s > 0; s >>= 1) {
        if (t < s) red[t] += red[t + s];
        __syncthreads();
    }
    float tr = red[0];
    float invTr = 1.f / tr;
    if (t == 0) gScale[g] = rsqrtf(tr);

    for (int e = t; e < 16384; e += 256) {
        int i = e >> 7, j = e & 127;
        float cv = (gSxx[g * 16384 + e] - (float)NTOT * mu[i] * mu[j]) / ((float)NTOT - 1.f);
        float ce = (1.f - EPSV) * cv + ((i == j) ? EPSV : 0.f);
        float sg = ce * invTr;
        gSigma[g * 16384 + e] = sg;
        gP[g * 16384 + e] = ((i == j) ? 1.5f : 0.f) - 0.5f * sg;
    }
}

// ---------------- K4: P2 = P@P, PS = P@Sigma ----------------
__global__ __launch_bounds__(256) void k_ns1(
    const float* __restrict__ gP, const float* __restrict__ gS,
    float* __restrict__ gP2, float* __restrict__ gPS)
{
    int g = blockIdx.y;
    int row = blockIdx.x * 8 + (threadIdx.x >> 5);
    int cq = (threadIdx.x & 31) * 4;
    const float* P = gP + g * 16384;
    const float* S = gS + g * 16384;
    f4 a1 = {0.f,0.f,0.f,0.f}, a2 = {0.f,0.f,0.f,0.f};
    for (int k = 0; k < 128; k += 4) {
        f4 a = ld4(&P[row * 128 + k]);
        float av[4] = {a.x, a.y, a.z, a.w};
#pragma unroll
        for (int kk = 0; kk < 4; ++kk) {
            f4 b1 = ld4(&P[(k + kk) * 128 + cq]);
            f4 b2 = ld4(&S[(k + kk) * 128 + cq]);
            float aa = av[kk];
            a1.x += aa * b1.x; a1.y += aa * b1.y; a1.z += aa * b1.z; a1.w += aa * b1.w;
            a2.x += aa * b2.x; a2.y += aa * b2.y; a2.z += aa * b2.z; a2.w += aa * b2.w;
        }
    }
    *(f4*)&gP2[g * 16384 + row * 128 + cq] = a1;
    *(f4*)&gPS[g * 16384 + row * 128 + cq] = a2;
}

// ---------------- K5: P = 1.5P - 0.5 * (P2 @ PS) ----------------
__global__ __launch_bounds__(256) void k_ns2(
    float* __restrict__ gP, const float* __restrict__ gP2, const float* __restrict__ gPS)
{
    int g = blockIdx.y;
    int row = blockIdx.x * 8 + (threadIdx.x >> 5);
    int cq = (threadIdx.x & 31) * 4;
    const float* A = gP2 + g * 16384;
    const float* B = gPS + g * 16384;
    f4 acc = {0.f,0.f,0.f,0.f};
    for (int k = 0; k < 128; k += 4) {
        f4 a = ld4(&A[row * 128 + k]);
        float av[4] = {a.x, a.y, a.z, a.w};
#pragma unroll
        for (int kk = 0; kk < 4; ++kk) {
            f4 b = ld4(&B[(k + kk) * 128 + cq]);
            float aa = av[kk];
            acc.x += aa * b.x; acc.y += aa * b.y; acc.z += aa * b.z; acc.w += aa * b.w;
        }
    }
    size_t off = (size_t)g * 16384 + row * 128 + cq;
    f4 p = ld4(&gP[off]);
    f4 r;
    r.x = 1.5f * p.x - 0.5f * acc.x;
    r.y = 1.5f * p.y - 0.5f * acc.y;
    r.z = 1.5f * p.z - 0.5f * acc.z;
    r.w = 1.5f * p.w - 0.5f * acc.w;
    *(f4*)&gP[off] = r;
}

// ---------------- K6: beta' = beta - gamma*(W@mu);  Wb = bf16(P*scale) ----------------
__global__ __launch_bounds__(256) void k_prep(
    const float* __restrict__ gP, const float* __restrict__ gMean,
    const float* __restrict__ gScale, const float* __restrict__ gamma,
    const float* __restrict__ beta, float* __restrict__ gBp,
    ushort* __restrict__ gWb)
{
    int g = blockIdx.x, t = threadIdx.x;
    float sc = gScale[g];
    if (t < 128) {
        float s = 0.f;
        for (int k = 0; k < 128; ++k)
            s += gMean[g * 128 + k] * gP[g * 16384 + k * 128 + t];  // P symmetric
        s *= sc;
        int cch = g * 128 + t;
        gBp[cch] = beta[cch] - gamma[cch] * s;
    }
    for (int e = t; e < 16384; e += 256)
        gWb[g * 16384 + e] = f2bf(gP[g * 16384 + e] * sc);
}

// ---------------- K7: out = gamma * (bf16(X) @ Wb) + beta'  (MFMA, no LDS) ----------------
// grid (NTOT/256, 4), block 512 (8 waves: 4 sample-quads x 2 col-halves).
__global__ __launch_bounds__(512) void k_apply(
    const float* __restrict__ x, const ushort* __restrict__ gWb,
    const float* __restrict__ gamma, const float* __restrict__ gBp,
    float* __restrict__ out)
{
    const int g = blockIdx.y;
    const int t = threadIdx.x, lane = t & 63, wid = t >> 6;
    const int wm = wid >> 1, wn = wid & 1;
    const int l15 = lane & 15, l4 = lane >> 4;
    const int s0 = blockIdx.x * 256 + wm * 64;

    // W fragments: B[k][j] = W[k][col]; W symmetric -> load rows contiguously.
    const ushort* Wg = gWb + g * 16384;
    bf16x8 wf[4][4];
#pragma unroll
    for (int kt = 0; kt < 4; ++kt)
#pragma unroll
        for (int tn = 0; tn < 4; ++tn)
            wf[kt][tn] = *(const bf16x8*)&Wg[(wn*64 + tn*16 + l15) * 128 + kt*32 + l4*8];

    float gm[4], bp[4];
#pragma unroll
    for (int tn = 0; tn < 4; ++tn) {
        int ch = g * MGRP + wn*64 + tn*16 + l15;
        gm[tn] = gamma[ch];
        bp[tn] = gBp[ch];
    }

#pragma unroll
    for (int tm = 0; tm < 4; ++tm) {
        const float* ap = x + (size_t)(s0 + tm*16 + l15) * CTOT + g * MGRP + l4*8;
        bf16x8 a[4];
#pragma unroll
        for (int kt = 0; kt < 4; ++kt) {
            f4 u0 = ld4(ap + kt*32);
            f4 u1 = ld4(ap + kt*32 + 4);
            union { bf16x8 v; ushort u[8]; } cv;
            cv.u[0] = f2bf(u0.x); cv.u[1] = f2bf(u0.y);
            cv.u[2] = f2bf(u0.z); cv.u[3] = f2bf(u0.w);
            cv.u[4] = f2bf(u1.x); cv.u[5] = f2bf(u1.y);
            cv.u[6] = f2bf(u1.z); cv.u[7] = f2bf(u1.w);
            a[kt] = cv.v;
        }
        f32x4 acc[4];
#pragma unroll
        for (int tn = 0; tn < 4; ++tn) acc[tn] = (f32x4){0.f, 0.f, 0.f, 0.f};
#pragma unroll
        for (int tn = 0; tn < 4; ++tn)
#pragma unroll
            for (int kt = 0; kt < 4; ++kt)
                acc[tn] = __builtin_amdgcn_mfma_f32_16x16x32_bf16(
                    a[kt], wf[kt][tn], acc[tn], 0, 0, 0);
#pragma unroll
        for (int tn = 0; tn < 4; ++tn)
#pragma unroll
            for (int r = 0; r < 4; ++r) {
                int row = s0 + tm*16 + l4*4 + r;
                out[(size_t)row * CTOT + g * MGRP + wn*64 + tn*16 + l15] =
                    gm[tn] * acc[tn][r] + bp[tn];
            }
    }
}

// ---------------- launch ----------------
extern "C" void kernel_launch(void* const* d_in, const int* in_sizes, int n_in,
                              void* d_out, int out_size, void* d_ws, size_t ws_size,
                              hipStream_t stream)
{
    const float* x     = (const float*)d_in[0];
    const float* gamma = (const float*)d_in[1];
    const float* beta  = (const float*)d_in[2];
    float* out = (float*)d_out;
    float* ws  = (float*)d_ws;

    int nchunk = 64;
    auto need = [](int nc) -> size_t {
        return ((size_t)nc * 4 * 16384 + (size_t)nc * 4 * 128 +
                5ull * 4 * 16384 + 512 + 16 + 512 + 32768) * 4;
    };
    while (nchunk > 8 && need(nchunk) > ws_size) nchunk >>= 1;
    int rowsPer = NTOT / nchunk;

    size_t off = 0;
    float* sxxPart = ws + off; off += (size_t)nchunk * 4 * 16384;
    float* sxPart  = ws + off; off += (size_t)nchunk * 4 * 128;
    float* gSxx    = ws + off; off += 4 * 16384;
    float* gSigma  = ws + off; off += 4 * 16384;
    float* gP      = ws + off; off += 4 * 16384;
    float* gP2     = ws + off; off += 4 * 16384;
    float* gPS     = ws + off; off += 4 * 16384;
    float* gMean   = ws + off; off += 512;
    float* gScale  = ws + off; off += 16;
    float* gBp     = ws + off; off += 512;
    ushort* gWb    = (ushort*)(ws + off); off += 32768;   // 4*16384 bf16

    k_cov<<<dim3(nchunk, 4), 512, 0, stream>>>(x, sxxPart, sxPart, nchunk, rowsPer);
    k_reduce<<<dim3(64, 4), 256, 0, stream>>>(sxxPart, gSxx, nchunk);
    k_finalize<<<4, 256, 0, stream>>>(gSxx, sxPart, gSigma, gP, gMean, gScale, nchunk);
    for (int it = 0; it < 2; ++it) {
        k_ns1<<<dim3(16, 4), 256, 0, stream>>>(gP, gSigma, gP2, gPS);
        k_ns2<<<dim3(16, 4), 256, 0, stream>>>(gP, gP2, gPS);
    }
    k_prep<<<4, 256, 0, stream>>>(gP, gMean, gScale, gamma, beta, gBp, gWb);
    k_apply<<<dim3(NTOT / 256, 4), 512, 0, stream>>>(x, gWb, gamma, gBp, out);
}